// Round 3
// baseline (163.350 us; speedup 1.0000x reference)
//
#include <hip/hip_runtime.h>

#define NN 768
#define FD 256
#define HD 128

__device__ __forceinline__ float relu(float x) { return x > 0.f ? x : 0.f; }
__device__ __forceinline__ void fma4(float4& a, float s, float4 v) {
    a.x = fmaf(s, v.x, a.x); a.y = fmaf(s, v.y, a.y);
    a.z = fmaf(s, v.z, a.z); a.w = fmaf(s, v.w, a.w);
}
__device__ __forceinline__ float rdot(float4 a, float4 b, float4 w) {
    float s = relu(a.x + b.x) * w.x;
    s = fmaf(relu(a.y + b.y), w.y, s);
    s = fmaf(relu(a.z + b.z), w.z, s);
    s = fmaf(relu(a.w + b.w), w.w, s);
    return s;
}

// K1: blocks 0..255 (768 thr): rows 3b..3b+2 -> dinv[i], t1 = dinv*(x@w1)
//     block 256: cvec[k] = temb[t]@we1[2H:] + be1   (unchanged — passed twice)
__global__ __launch_bounds__(768) void k_prep(
        const float* __restrict__ x, const float* __restrict__ adj,
        const float* __restrict__ w1, const float* __restrict__ temb,
        const float* __restrict__ we1, const float* __restrict__ be1,
        const int* __restrict__ tptr, float* __restrict__ dinv,
        float* __restrict__ cvec, float* __restrict__ t1D) {
    int b = blockIdx.x, tid = threadIdx.x;
    if (b == 256) {
        __shared__ float ts[HD];
        if (tid < HD) ts[tid] = temb[tptr[0] * HD + tid];
        __syncthreads();
        if (tid < HD) {
            float a0 = be1[tid], a1 = 0.f, a2 = 0.f, a3 = 0.f;
            for (int m = 0; m < HD; m += 4) {
                a0 = fmaf(ts[m + 0], we1[(2 * HD + m + 0) * HD + tid], a0);
                a1 = fmaf(ts[m + 1], we1[(2 * HD + m + 1) * HD + tid], a1);
                a2 = fmaf(ts[m + 2], we1[(2 * HD + m + 2) * HD + tid], a2);
                a3 = fmaf(ts[m + 3], we1[(2 * HD + m + 3) * HD + tid], a3);
            }
            cvec[tid] = (a0 + a1) + (a2 + a3);
        }
        return;
    }
    int i0 = b * 3;
    __shared__ float xs[3][FD];
    __shared__ float part[3][2][HD];
    __shared__ float red[12];
    __shared__ float sdi[3];
    if (tid < 192) {
        int row = tid >> 6, m4 = tid & 63;
        *(float4*)&xs[row][m4 * 4] = *(const float4*)&x[(i0 + row) * FD + m4 * 4];
    }
    {
        int r2 = tid >> 8, s = tid & 255;
        float sum = 0.f;
        if (s < 192) {
            float4 a = *(const float4*)&adj[(i0 + r2) * NN + s * 4];
            sum = (a.x + a.y) + (a.z + a.w);
        }
#pragma unroll
        for (int off = 32; off > 0; off >>= 1) sum += __shfl_down(sum, off, 64);
        if ((tid & 63) == 0) red[tid >> 6] = sum;
    }
    __syncthreads();
    if (tid < 3) {
        float t = (red[4 * tid] + red[4 * tid + 1]) + (red[4 * tid + 2] + red[4 * tid + 3]);
        float d = rsqrtf(t + 1.f);
        sdi[tid] = d; dinv[i0 + tid] = d;
    }
    __syncthreads();
    int r = tid >> 8, half = (tid >> 7) & 1, k = tid & 127;
    float a0 = 0.f, a1 = 0.f, a2 = 0.f, a3 = 0.f;
    for (int g = 128 * half; g < 128 * half + 128; g += 16) {
        float wv[16];
#pragma unroll
        for (int u = 0; u < 16; ++u) wv[u] = w1[(g + u) * HD + k];
#pragma unroll
        for (int u = 0; u < 16; ++u) {
            float xv = xs[r][g + u];
            if ((u & 3) == 0) a0 = fmaf(xv, wv[u], a0);
            else if ((u & 3) == 1) a1 = fmaf(xv, wv[u], a1);
            else if ((u & 3) == 2) a2 = fmaf(xv, wv[u], a2);
            else a3 = fmaf(xv, wv[u], a3);
        }
    }
    part[r][half][k] = (a0 + a1) + (a2 + a3);
    __syncthreads();
    if (half == 0) t1D[(i0 + r) * HD + k] = sdi[r] * (part[r][0][k] + part[r][1][k]);
}

// Full-K GCN aggregation for 3 rows, 512 threads (8 waves/CU for latency hiding):
// gs[r][k] = relu(dinv[i]*(sum_j adj[i,j]*tin[j,k] + tin[i,k]))
__device__ __forceinline__ void gcn_agg512(
        float* __restrict__ a0s, float* __restrict__ a1s, float* __restrict__ a2s,
        float (*part)[3][HD], float (*gs)[HD],
        const float* __restrict__ adj, const float* __restrict__ tin,
        const float* __restrict__ dinv, int i0, int tid) {
    for (int j = tid; j < NN; j += 512) {
        a0s[j] = adj[(i0 + 0) * NN + j];
        a1s[j] = adj[(i0 + 1) * NN + j];
        a2s[j] = adj[(i0 + 2) * NN + j];
    }
    __syncthreads();
    int k4 = tid & 31, jc = tid >> 5;                // 16 j-chunks x 48 j
    float4 acc0 = {0,0,0,0}, acc1 = {0,0,0,0}, acc2 = {0,0,0,0};
    const float* tb = tin + k4 * 4;
#pragma unroll 4
    for (int jj = 0; jj < 48; ++jj) {
        int j = jc * 48 + jj;
        float4 tv = *(const float4*)&tb[j * HD];     // 512B contiguous per 32-lane group, L2-hit
        fma4(acc0, a0s[j], tv);                      // LDS broadcast
        fma4(acc1, a1s[j], tv);
        fma4(acc2, a2s[j], tv);
    }
    *(float4*)&part[jc][0][k4 * 4] = acc0;
    *(float4*)&part[jc][1][k4 * 4] = acc1;
    *(float4*)&part[jc][2][k4 * 4] = acc2;
    __syncthreads();
    if (tid < 3 * HD) {
        int r = tid >> 7, k = tid & 127;
        float s = tin[(i0 + r) * HD + k];            // self loop (adj + I)
#pragma unroll
        for (int c = 0; c < 16; ++c) s += part[c][r][k];
        gs[r][k] = relu(dinv[i0 + r] * s);
    }
    __syncthreads();
}

// K2: g1 = relu(dinv*(A@t1)); t2 = dinv*(g1@w2).  256 blocks x 512 thr, 3 rows each.
__global__ __launch_bounds__(512) void k_layer1(
        const float* __restrict__ adj, const float* __restrict__ t1,
        const float* __restrict__ dinv, const float* __restrict__ w2,
        float* __restrict__ t2) {
    __shared__ float a0s[NN], a1s[NN], a2s[NN];
    __shared__ float part[16][3][HD];
    __shared__ float gs[3][HD];
    int tid = threadIdx.x, i0 = blockIdx.x * 3;
    gcn_agg512(a0s, a1s, a2s, part, gs, adj, t1, dinv, i0, tid);
    if (tid < 3 * HD) {
        int r = tid >> 7, k = tid & 127;
        float acc = 0.f;
        const float* wc = w2 + k;
#pragma unroll
        for (int m4 = 0; m4 < 32; ++m4) {
            float4 gv = *(float4*)&gs[r][m4 * 4];    // LDS broadcast
            acc = fmaf(gv.x, wc[(m4 * 4 + 0) * HD], acc);
            acc = fmaf(gv.y, wc[(m4 * 4 + 1) * HD], acc);
            acc = fmaf(gv.z, wc[(m4 * 4 + 2) * HD], acc);
            acc = fmaf(gv.w, wc[(m4 * 4 + 3) * HD], acc);
        }
        t2[(i0 + r) * HD + k] = dinv[i0 + r] * acc;
    }
}

// K3: g2 = relu(dinv*(A@t2)); p = g2@we1[:H]+cvec, q = g2@we1[H:2H].
__global__ __launch_bounds__(512) void k_layer2(
        const float* __restrict__ adj, const float* __restrict__ t2,
        const float* __restrict__ dinv, const float* __restrict__ we1,
        const float* __restrict__ cvec, float* __restrict__ p, float* __restrict__ q) {
    __shared__ float a0s[NN], a1s[NN], a2s[NN];
    __shared__ float part[16][3][HD];
    __shared__ float gs[3][HD];
    int tid = threadIdx.x, i0 = blockIdx.x * 3;
    gcn_agg512(a0s, a1s, a2s, part, gs, adj, t2, dinv, i0, tid);
    if (tid < 3 * HD) {
        int r = tid >> 7, k = tid & 127;
        float ap = 0.f, aq = 0.f;
        const float* wp = we1 + k;
        const float* wq = we1 + HD * HD + k;
#pragma unroll
        for (int m4 = 0; m4 < 32; ++m4) {
            float4 gv = *(float4*)&gs[r][m4 * 4];
            ap = fmaf(gv.x, wp[(m4 * 4 + 0) * HD], ap); aq = fmaf(gv.x, wq[(m4 * 4 + 0) * HD], aq);
            ap = fmaf(gv.y, wp[(m4 * 4 + 1) * HD], ap); aq = fmaf(gv.y, wq[(m4 * 4 + 1) * HD], aq);
            ap = fmaf(gv.z, wp[(m4 * 4 + 2) * HD], ap); aq = fmaf(gv.z, wq[(m4 * 4 + 2) * HD], aq);
            ap = fmaf(gv.w, wp[(m4 * 4 + 3) * HD], ap); aq = fmaf(gv.w, wq[(m4 * 4 + 3) * HD], aq);
        }
        p[(i0 + r) * HD + k] = ap + cvec[k];
        q[(i0 + r) * HD + k] = aq;
    }
}

// K4: 16x16 tile pairs (bi<=bj), 48*49/2 = 1176 blocks, 256 thr, 1 pair/thread.
// ~4.6 blocks/CU in flight (LDS 35.4 KB -> 4 resident) vs old 300-block 2x-tail.
__global__ __launch_bounds__(256) void k_pair(
        const float* __restrict__ p, const float* __restrict__ q,
        const float* __restrict__ we2, const float* __restrict__ be2,
        float* __restrict__ out) {
    int t = blockIdx.x;
    int bj = (int)((sqrtf(8.f * t + 1.f) - 1.f) * 0.5f);
    while ((bj + 1) * (bj + 2) / 2 <= t) ++bj;
    while (bj * (bj + 1) / 2 > t) --bj;
    int bi = t - bj * (bj + 1) / 2;
    int i0 = bi * 16, j0 = bj * 16;
    __shared__ float spi[16][132], sqi[16][132], spj[16][132], sqj[16][132];
    __shared__ float w2s[HD];
    __shared__ float vt[16][17];
    int tid = threadIdx.x;
    if (tid < HD) w2s[tid] = we2[tid];
    for (int idx = tid; idx < 512; idx += 256) {
        int r = idx >> 5, c4 = idx & 31;
        *(float4*)&spi[r][c4 * 4] = *(const float4*)&p[(i0 + r) * HD + c4 * 4];
        *(float4*)&sqi[r][c4 * 4] = *(const float4*)&q[(i0 + r) * HD + c4 * 4];
        *(float4*)&spj[r][c4 * 4] = *(const float4*)&p[(j0 + r) * HD + c4 * 4];
        *(float4*)&sqj[r][c4 * 4] = *(const float4*)&q[(j0 + r) * HD + c4 * 4];
    }
    __syncthreads();
    int tx = tid & 15, ty = tid >> 4;   // i-row = i0+ty, j-row = j0+tx
    float aij = 0.f, aji = 0.f;
#pragma unroll 8
    for (int k4 = 0; k4 < 32; ++k4) {
        float4 w  = *(float4*)&w2s[k4 * 4];
        float4 Pi = *(float4*)&spi[ty][k4 * 4];
        float4 Qj = *(float4*)&sqj[tx][k4 * 4];
        float4 Pj = *(float4*)&spj[tx][k4 * 4];
        float4 Qi = *(float4*)&sqi[ty][k4 * 4];
        aij += rdot(Pi, Qj, w);
        aji += rdot(Pj, Qi, w);
    }
    float bias = be2[0];
    float v = 0.5f * (1.f / (1.f + __expf(-(aij + bias)))
                    + 1.f / (1.f + __expf(-(aji + bias))));
    out[(i0 + ty) * NN + (j0 + tx)] = v;   // coalesced row write
    vt[tx][ty] = v;                        // stage transpose in LDS
    __syncthreads();
    out[(j0 + ty) * NN + (i0 + tx)] = vt[ty][tx];  // coalesced transposed write
}

extern "C" void kernel_launch(void* const* d_in, const int* in_sizes, int n_in,
                              void* d_out, int out_size, void* d_ws, size_t ws_size,
                              hipStream_t stream) {
    const float* x    = (const float*)d_in[0];
    const float* adj  = (const float*)d_in[1];
    const float* w1   = (const float*)d_in[2];
    const float* w2   = (const float*)d_in[3];
    const float* temb = (const float*)d_in[4];
    const float* we1  = (const float*)d_in[5];
    const float* be1  = (const float*)d_in[6];
    const float* we2  = (const float*)d_in[7];
    const float* be2  = (const float*)d_in[8];
    const int* tptr   = (const int*)d_in[9];
    float* out        = (float*)d_out;

    float* ws   = (float*)d_ws;
    float* dinv = ws;               // 768
    float* cvec = ws + 768;         // 128
    float* t1   = ws + 1024;        // 768*128
    float* t2   = t1 + NN * HD;
    float* p    = t2 + NN * HD;
    float* q    = p + NN * HD;

    k_prep  <<<257, 768, 0, stream>>>(x, adj, w1, temb, we1, be1, tptr, dinv, cvec, t1);
    k_layer1<<<256, 512, 0, stream>>>(adj, t1, dinv, w2, t2);
    k_layer2<<<256, 512, 0, stream>>>(adj, t2, dinv, we1, cvec, p, q);
    k_pair  <<<1176, 256, 0, stream>>>(p, q, we2, be2, out);
}

// Round 4
// 116.360 us; speedup vs baseline: 1.4038x; 1.4038x over previous
//
#include <hip/hip_runtime.h>

#define NN 768
#define FD 256
#define HD 128

__device__ __forceinline__ float relu(float x) { return x > 0.f ? x : 0.f; }
__device__ __forceinline__ void fma4(float4& a, float s, float4 v) {
    a.x = fmaf(s, v.x, a.x); a.y = fmaf(s, v.y, a.y);
    a.z = fmaf(s, v.z, a.z); a.w = fmaf(s, v.w, a.w);
}
__device__ __forceinline__ float rdot(float4 a, float4 b, float4 w) {
    float s = relu(a.x + b.x) * w.x;
    s = fmaf(relu(a.y + b.y), w.y, s);
    s = fmaf(relu(a.z + b.z), w.z, s);
    s = fmaf(relu(a.w + b.w), w.w, s);
    return s;
}

// K1: blocks 0..255 (768 thr): rows 3b..3b+2 -> dinv[i], t1 = dinv*(x@w1)
//     block 256: cvec[k] = temb[t]@we1[2H:] + be1
__global__ __launch_bounds__(768) void k_prep(
        const float* __restrict__ x, const float* __restrict__ adj,
        const float* __restrict__ w1, const float* __restrict__ temb,
        const float* __restrict__ we1, const float* __restrict__ be1,
        const int* __restrict__ tptr, float* __restrict__ dinv,
        float* __restrict__ cvec, float* __restrict__ t1D) {
    int b = blockIdx.x, tid = threadIdx.x;
    if (b == 256) {
        __shared__ float ts[HD];
        if (tid < HD) ts[tid] = temb[tptr[0] * HD + tid];
        __syncthreads();
        if (tid < HD) {
            float a0 = be1[tid], a1 = 0.f, a2 = 0.f, a3 = 0.f;
            for (int m = 0; m < HD; m += 4) {
                a0 = fmaf(ts[m + 0], we1[(2 * HD + m + 0) * HD + tid], a0);
                a1 = fmaf(ts[m + 1], we1[(2 * HD + m + 1) * HD + tid], a1);
                a2 = fmaf(ts[m + 2], we1[(2 * HD + m + 2) * HD + tid], a2);
                a3 = fmaf(ts[m + 3], we1[(2 * HD + m + 3) * HD + tid], a3);
            }
            cvec[tid] = (a0 + a1) + (a2 + a3);
        }
        return;
    }
    int i0 = b * 3;
    __shared__ float xs[3][FD];
    __shared__ float part[3][2][HD];
    __shared__ float red[12];
    __shared__ float sdi[3];
    if (tid < 192) {
        int row = tid >> 6, m4 = tid & 63;
        *(float4*)&xs[row][m4 * 4] = *(const float4*)&x[(i0 + row) * FD + m4 * 4];
    }
    {
        int r2 = tid >> 8, s = tid & 255;
        float sum = 0.f;
        if (s < 192) {
            float4 a = *(const float4*)&adj[(i0 + r2) * NN + s * 4];
            sum = (a.x + a.y) + (a.z + a.w);
        }
#pragma unroll
        for (int off = 32; off > 0; off >>= 1) sum += __shfl_down(sum, off, 64);
        if ((tid & 63) == 0) red[tid >> 6] = sum;
    }
    __syncthreads();
    if (tid < 3) {
        float t = (red[4 * tid] + red[4 * tid + 1]) + (red[4 * tid + 2] + red[4 * tid + 3]);
        float d = rsqrtf(t + 1.f);
        sdi[tid] = d; dinv[i0 + tid] = d;
    }
    __syncthreads();
    int r = tid >> 8, half = (tid >> 7) & 1, k = tid & 127;
    float a0 = 0.f, a1 = 0.f, a2 = 0.f, a3 = 0.f;
    for (int g = 128 * half; g < 128 * half + 128; g += 16) {
        float wv[16];
#pragma unroll
        for (int u = 0; u < 16; ++u) wv[u] = w1[(g + u) * HD + k];
#pragma unroll
        for (int u = 0; u < 16; ++u) {
            float xv = xs[r][g + u];
            if ((u & 3) == 0) a0 = fmaf(xv, wv[u], a0);
            else if ((u & 3) == 1) a1 = fmaf(xv, wv[u], a1);
            else if ((u & 3) == 2) a2 = fmaf(xv, wv[u], a2);
            else a3 = fmaf(xv, wv[u], a3);
        }
    }
    part[r][half][k] = (a0 + a1) + (a2 + a3);
    __syncthreads();
    if (half == 0) t1D[(i0 + r) * HD + k] = sdi[r] * (part[r][0][k] + part[r][1][k]);
}

// GCN aggregation, 256 thr, 3 rows/block. Register-batched loads (14 in flight),
// block-staggered j-ranges (identical arithmetic: group jc handles range (jc+b)&7
// and writes part[(jc+b)&7]), adj read as half-wave-uniform global float4.
__device__ __forceinline__ void gcn_agg(
        float (*part)[3][HD], float (*gs)[HD],
        const float* __restrict__ adj, const float* __restrict__ tin,
        const float* __restrict__ dinv, int i0, int tid, int b) {
    int k4 = tid & 31, jc = tid >> 5;
    int seg = (jc + b) & 7;                   // staggered segment label
    int jbase = seg * 96;
    const float* tb = tin + k4 * 4;
    const float* ar0 = adj + (i0 + 0) * NN;
    const float* ar1 = adj + (i0 + 1) * NN;
    const float* ar2 = adj + (i0 + 2) * NN;
    float4 acc0 = {0,0,0,0}, acc1 = {0,0,0,0}, acc2 = {0,0,0,0};
    for (int it = 0; it < 12; ++it) {
        int j = jbase + it * 8;
        float4 a0A = *(const float4*)&ar0[j];
        float4 a0B = *(const float4*)&ar0[j + 4];
        float4 a1A = *(const float4*)&ar1[j];
        float4 a1B = *(const float4*)&ar1[j + 4];
        float4 a2A = *(const float4*)&ar2[j];
        float4 a2B = *(const float4*)&ar2[j + 4];
        float4 t0 = *(const float4*)&tb[(j + 0) * HD];
        float4 t1 = *(const float4*)&tb[(j + 1) * HD];
        float4 t2 = *(const float4*)&tb[(j + 2) * HD];
        float4 t3 = *(const float4*)&tb[(j + 3) * HD];
        float4 t4 = *(const float4*)&tb[(j + 4) * HD];
        float4 t5 = *(const float4*)&tb[(j + 5) * HD];
        float4 t6 = *(const float4*)&tb[(j + 6) * HD];
        float4 t7 = *(const float4*)&tb[(j + 7) * HD];
        fma4(acc0, a0A.x, t0); fma4(acc0, a0A.y, t1); fma4(acc0, a0A.z, t2); fma4(acc0, a0A.w, t3);
        fma4(acc0, a0B.x, t4); fma4(acc0, a0B.y, t5); fma4(acc0, a0B.z, t6); fma4(acc0, a0B.w, t7);
        fma4(acc1, a1A.x, t0); fma4(acc1, a1A.y, t1); fma4(acc1, a1A.z, t2); fma4(acc1, a1A.w, t3);
        fma4(acc1, a1B.x, t4); fma4(acc1, a1B.y, t5); fma4(acc1, a1B.z, t6); fma4(acc1, a1B.w, t7);
        fma4(acc2, a2A.x, t0); fma4(acc2, a2A.y, t1); fma4(acc2, a2A.z, t2); fma4(acc2, a2A.w, t3);
        fma4(acc2, a2B.x, t4); fma4(acc2, a2B.y, t5); fma4(acc2, a2B.z, t6); fma4(acc2, a2B.w, t7);
    }
    *(float4*)&part[seg][0][k4 * 4] = acc0;
    *(float4*)&part[seg][1][k4 * 4] = acc1;
    *(float4*)&part[seg][2][k4 * 4] = acc2;
    __syncthreads();
    for (int idx = tid; idx < 3 * HD; idx += 256) {
        int r = idx >> 7, k = idx & 127;
        float s = tin[(i0 + r) * HD + k];      // self loop (adj + I)
#pragma unroll
        for (int c = 0; c < 8; ++c) s += part[c][r][k];
        gs[r][k] = relu(dinv[i0 + r] * s);
    }
    __syncthreads();
}

// K2: g1 = relu(dinv*(A@t1)); t2 = dinv*(g1@w2).  256 blocks x 256 thr.
__global__ __launch_bounds__(256) void k_layer1(
        const float* __restrict__ adj, const float* __restrict__ t1,
        const float* __restrict__ dinv, const float* __restrict__ w2,
        float* __restrict__ t2) {
    __shared__ float part[8][3][HD];
    __shared__ float gs[3][HD];
    int tid = threadIdx.x, i0 = blockIdx.x * 3;
    gcn_agg(part, gs, adj, t1, dinv, i0, tid, blockIdx.x);
    for (int idx = tid; idx < 3 * HD; idx += 256) {
        int r = idx >> 7, k = idx & 127;
        float acc = 0.f;
        const float* wc = w2 + k;
#pragma unroll
        for (int m4 = 0; m4 < 32; ++m4) {
            float4 gv = *(float4*)&gs[r][m4 * 4];   // LDS broadcast
            acc = fmaf(gv.x, wc[(m4 * 4 + 0) * HD], acc);
            acc = fmaf(gv.y, wc[(m4 * 4 + 1) * HD], acc);
            acc = fmaf(gv.z, wc[(m4 * 4 + 2) * HD], acc);
            acc = fmaf(gv.w, wc[(m4 * 4 + 3) * HD], acc);
        }
        t2[(i0 + r) * HD + k] = dinv[i0 + r] * acc;
    }
}

// K3: g2 = relu(dinv*(A@t2)); p = g2@we1[:H]+cvec, q = g2@we1[H:2H].
__global__ __launch_bounds__(256) void k_layer2(
        const float* __restrict__ adj, const float* __restrict__ t2,
        const float* __restrict__ dinv, const float* __restrict__ we1,
        const float* __restrict__ cvec, float* __restrict__ p, float* __restrict__ q) {
    __shared__ float part[8][3][HD];
    __shared__ float gs[3][HD];
    int tid = threadIdx.x, i0 = blockIdx.x * 3;
    gcn_agg(part, gs, adj, t2, dinv, i0, tid, blockIdx.x);
    for (int idx = tid; idx < 3 * HD; idx += 256) {
        int r = idx >> 7, k = idx & 127;
        float ap = 0.f, aq = 0.f;
        const float* wp = we1 + k;
        const float* wq = we1 + HD * HD + k;
#pragma unroll
        for (int m4 = 0; m4 < 32; ++m4) {
            float4 gv = *(float4*)&gs[r][m4 * 4];
            ap = fmaf(gv.x, wp[(m4 * 4 + 0) * HD], ap); aq = fmaf(gv.x, wq[(m4 * 4 + 0) * HD], aq);
            ap = fmaf(gv.y, wp[(m4 * 4 + 1) * HD], ap); aq = fmaf(gv.y, wq[(m4 * 4 + 1) * HD], aq);
            ap = fmaf(gv.z, wp[(m4 * 4 + 2) * HD], ap); aq = fmaf(gv.z, wq[(m4 * 4 + 2) * HD], aq);
            ap = fmaf(gv.w, wp[(m4 * 4 + 3) * HD], ap); aq = fmaf(gv.w, wq[(m4 * 4 + 3) * HD], aq);
        }
        p[(i0 + r) * HD + k] = ap + cvec[k];
        q[(i0 + r) * HD + k] = aq;
    }
}

// K4: 16x16 tile pairs (bi<=bj), 1176 blocks, 256 thr, 1 pair/thread.
__global__ __launch_bounds__(256) void k_pair(
        const float* __restrict__ p, const float* __restrict__ q,
        const float* __restrict__ we2, const float* __restrict__ be2,
        float* __restrict__ out) {
    int t = blockIdx.x;
    int bj = (int)((sqrtf(8.f * t + 1.f) - 1.f) * 0.5f);
    while ((bj + 1) * (bj + 2) / 2 <= t) ++bj;
    while (bj * (bj + 1) / 2 > t) --bj;
    int bi = t - bj * (bj + 1) / 2;
    int i0 = bi * 16, j0 = bj * 16;
    __shared__ float spi[16][132], sqi[16][132], spj[16][132], sqj[16][132];
    __shared__ float w2s[HD];
    __shared__ float vt[16][17];
    int tid = threadIdx.x;
    if (tid < HD) w2s[tid] = we2[tid];
    for (int idx = tid; idx < 512; idx += 256) {
        int r = idx >> 5, c4 = idx & 31;
        *(float4*)&spi[r][c4 * 4] = *(const float4*)&p[(i0 + r) * HD + c4 * 4];
        *(float4*)&sqi[r][c4 * 4] = *(const float4*)&q[(i0 + r) * HD + c4 * 4];
        *(float4*)&spj[r][c4 * 4] = *(const float4*)&p[(j0 + r) * HD + c4 * 4];
        *(float4*)&sqj[r][c4 * 4] = *(const float4*)&q[(j0 + r) * HD + c4 * 4];
    }
    __syncthreads();
    int tx = tid & 15, ty = tid >> 4;
    float aij = 0.f, aji = 0.f;
#pragma unroll 8
    for (int k4 = 0; k4 < 32; ++k4) {
        float4 w  = *(float4*)&w2s[k4 * 4];
        float4 Pi = *(float4*)&spi[ty][k4 * 4];
        float4 Qj = *(float4*)&sqj[tx][k4 * 4];
        float4 Pj = *(float4*)&spj[tx][k4 * 4];
        float4 Qi = *(float4*)&sqi[ty][k4 * 4];
        aij += rdot(Pi, Qj, w);
        aji += rdot(Pj, Qi, w);
    }
    float bias = be2[0];
    float v = 0.5f * (1.f / (1.f + __expf(-(aij + bias)))
                    + 1.f / (1.f + __expf(-(aji + bias))));
    out[(i0 + ty) * NN + (j0 + tx)] = v;
    vt[tx][ty] = v;
    __syncthreads();
    out[(j0 + ty) * NN + (i0 + tx)] = vt[ty][tx];
}

extern "C" void kernel_launch(void* const* d_in, const int* in_sizes, int n_in,
                              void* d_out, int out_size, void* d_ws, size_t ws_size,
                              hipStream_t stream) {
    const float* x    = (const float*)d_in[0];
    const float* adj  = (const float*)d_in[1];
    const float* w1   = (const float*)d_in[2];
    const float* w2   = (const float*)d_in[3];
    const float* temb = (const float*)d_in[4];
    const float* we1  = (const float*)d_in[5];
    const float* be1  = (const float*)d_in[6];
    const float* we2  = (const float*)d_in[7];
    const float* be2  = (const float*)d_in[8];
    const int* tptr   = (const int*)d_in[9];
    float* out        = (float*)d_out;

    float* ws   = (float*)d_ws;
    float* dinv = ws;               // 768
    float* cvec = ws + 768;         // 128
    float* t1   = ws + 1024;        // 768*128
    float* t2   = t1 + NN * HD;
    float* p    = t2 + NN * HD;
    float* q    = p + NN * HD;

    k_prep  <<<257, 768, 0, stream>>>(x, adj, w1, temb, we1, be1, tptr, dinv, cvec, t1);
    k_layer1<<<256, 256, 0, stream>>>(adj, t1, dinv, w2, t2);
    k_layer2<<<256, 256, 0, stream>>>(adj, t2, dinv, we1, cvec, p, q);
    k_pair  <<<1176, 256, 0, stream>>>(p, q, we2, be2, out);
}

// Round 5
// 112.894 us; speedup vs baseline: 1.4469x; 1.0307x over previous
//
#include <hip/hip_runtime.h>

#define NN 768
#define FD 256
#define HD 128

__device__ __forceinline__ float relu(float x) { return x > 0.f ? x : 0.f; }
__device__ __forceinline__ void fma4(float4& a, float s, float4 v) {
    a.x = fmaf(s, v.x, a.x); a.y = fmaf(s, v.y, a.y);
    a.z = fmaf(s, v.z, a.z); a.w = fmaf(s, v.w, a.w);
}
__device__ __forceinline__ float rdot(float4 a, float4 b, float4 w) {
    float s = relu(a.x + b.x) * w.x;
    s = fmaf(relu(a.y + b.y), w.y, s);
    s = fmaf(relu(a.z + b.z), w.z, s);
    s = fmaf(relu(a.w + b.w), w.w, s);
    return s;
}

// K1: blocks 0..255 (768 thr): rows 3b..3b+2 -> dinv[i], t1 = dinv*(x@w1)
//     block 256: cvec[k] = temb[t]@we1[2H:] + be1
// x@w1 phase: 512 threads = 4 m-chunks x 128 k; each thread does ALL 3 rows from
// one w1 load (w1 traffic 3x lower than per-row threads).
__global__ __launch_bounds__(768) void k_prep(
        const float* __restrict__ x, const float* __restrict__ adj,
        const float* __restrict__ w1, const float* __restrict__ temb,
        const float* __restrict__ we1, const float* __restrict__ be1,
        const int* __restrict__ tptr, float* __restrict__ dinv,
        float* __restrict__ cvec, float* __restrict__ t1D) {
    int b = blockIdx.x, tid = threadIdx.x;
    if (b == 256) {
        __shared__ float ts[HD];
        if (tid < HD) ts[tid] = temb[tptr[0] * HD + tid];
        __syncthreads();
        if (tid < HD) {
            float a0 = be1[tid], a1 = 0.f, a2 = 0.f, a3 = 0.f;
            for (int m = 0; m < HD; m += 4) {
                a0 = fmaf(ts[m + 0], we1[(2 * HD + m + 0) * HD + tid], a0);
                a1 = fmaf(ts[m + 1], we1[(2 * HD + m + 1) * HD + tid], a1);
                a2 = fmaf(ts[m + 2], we1[(2 * HD + m + 2) * HD + tid], a2);
                a3 = fmaf(ts[m + 3], we1[(2 * HD + m + 3) * HD + tid], a3);
            }
            cvec[tid] = (a0 + a1) + (a2 + a3);
        }
        return;
    }
    int i0 = b * 3;
    __shared__ float xs[3][FD];
    __shared__ float partw[4][3][HD];
    __shared__ float red[12];
    __shared__ float sdi[3];
    if (tid < 192) {
        int row = tid >> 6, m4 = tid & 63;
        *(float4*)&xs[row][m4 * 4] = *(const float4*)&x[(i0 + row) * FD + m4 * 4];
    }
    {
        int r2 = tid >> 8, s = tid & 255;
        float sum = 0.f;
        if (s < 192) {
            float4 a = *(const float4*)&adj[(i0 + r2) * NN + s * 4];
            sum = (a.x + a.y) + (a.z + a.w);
        }
#pragma unroll
        for (int off = 32; off > 0; off >>= 1) sum += __shfl_down(sum, off, 64);
        if ((tid & 63) == 0) red[tid >> 6] = sum;
    }
    __syncthreads();
    if (tid < 3) {
        float t = (red[4 * tid] + red[4 * tid + 1]) + (red[4 * tid + 2] + red[4 * tid + 3]);
        float d = rsqrtf(t + 1.f);
        sdi[tid] = d; dinv[i0 + tid] = d;
    }
    if (tid < 512) {
        int k = tid & 127, c = tid >> 7;          // m-chunk c*64..c*64+63
        float acc0 = 0.f, acc1 = 0.f, acc2 = 0.f;
        for (int g = c * 64; g < c * 64 + 64; g += 16) {
            float wv[16];
#pragma unroll
            for (int u = 0; u < 16; ++u) wv[u] = w1[(g + u) * HD + k];
#pragma unroll
            for (int u = 0; u < 16; ++u) {
                acc0 = fmaf(xs[0][g + u], wv[u], acc0);
                acc1 = fmaf(xs[1][g + u], wv[u], acc1);
                acc2 = fmaf(xs[2][g + u], wv[u], acc2);
            }
        }
        partw[c][0][k] = acc0;
        partw[c][1][k] = acc1;
        partw[c][2][k] = acc2;
    }
    __syncthreads();
    if (tid < 384) {
        int r = tid >> 7, k = tid & 127;
        float s = (partw[0][r][k] + partw[1][r][k]) + (partw[2][r][k] + partw[3][r][k]);
        t1D[(i0 + r) * HD + k] = sdi[r] * s;
    }
}

// GCN aggregation, 512 thr (2 waves/SIMD for latency overlap), 3 rows/block.
// 16 j-chunks x 48 j, register-batched 8-j iterations (14 loads in flight),
// block-staggered segment labels (identical arithmetic), adj as uniform float4.
__device__ __forceinline__ void gcn_agg(
        float (*part)[3][HD], float (*gs)[HD],
        const float* __restrict__ adj, const float* __restrict__ tin,
        const float* __restrict__ dinv, int i0, int tid, int b) {
    int k4 = tid & 31, jc = tid >> 5;           // jc 0..15
    int seg = (jc + b) & 15;                    // staggered segment label
    int jbase = seg * 48;
    const float* tb = tin + k4 * 4;
    const float* ar0 = adj + (i0 + 0) * NN;
    const float* ar1 = adj + (i0 + 1) * NN;
    const float* ar2 = adj + (i0 + 2) * NN;
    float4 acc0 = {0,0,0,0}, acc1 = {0,0,0,0}, acc2 = {0,0,0,0};
    for (int it = 0; it < 6; ++it) {
        int j = jbase + it * 8;
        float4 a0A = *(const float4*)&ar0[j];
        float4 a0B = *(const float4*)&ar0[j + 4];
        float4 a1A = *(const float4*)&ar1[j];
        float4 a1B = *(const float4*)&ar1[j + 4];
        float4 a2A = *(const float4*)&ar2[j];
        float4 a2B = *(const float4*)&ar2[j + 4];
        float4 t0 = *(const float4*)&tb[(j + 0) * HD];
        float4 t1 = *(const float4*)&tb[(j + 1) * HD];
        float4 t2 = *(const float4*)&tb[(j + 2) * HD];
        float4 t3 = *(const float4*)&tb[(j + 3) * HD];
        float4 t4 = *(const float4*)&tb[(j + 4) * HD];
        float4 t5 = *(const float4*)&tb[(j + 5) * HD];
        float4 t6 = *(const float4*)&tb[(j + 6) * HD];
        float4 t7 = *(const float4*)&tb[(j + 7) * HD];
        fma4(acc0, a0A.x, t0); fma4(acc0, a0A.y, t1); fma4(acc0, a0A.z, t2); fma4(acc0, a0A.w, t3);
        fma4(acc0, a0B.x, t4); fma4(acc0, a0B.y, t5); fma4(acc0, a0B.z, t6); fma4(acc0, a0B.w, t7);
        fma4(acc1, a1A.x, t0); fma4(acc1, a1A.y, t1); fma4(acc1, a1A.z, t2); fma4(acc1, a1A.w, t3);
        fma4(acc1, a1B.x, t4); fma4(acc1, a1B.y, t5); fma4(acc1, a1B.z, t6); fma4(acc1, a1B.w, t7);
        fma4(acc2, a2A.x, t0); fma4(acc2, a2A.y, t1); fma4(acc2, a2A.z, t2); fma4(acc2, a2A.w, t3);
        fma4(acc2, a2B.x, t4); fma4(acc2, a2B.y, t5); fma4(acc2, a2B.z, t6); fma4(acc2, a2B.w, t7);
    }
    *(float4*)&part[seg][0][k4 * 4] = acc0;
    *(float4*)&part[seg][1][k4 * 4] = acc1;
    *(float4*)&part[seg][2][k4 * 4] = acc2;
    __syncthreads();
    if (tid < 3 * HD) {
        int r = tid >> 7, k = tid & 127;
        float s = tin[(i0 + r) * HD + k];       // self loop (adj + I)
#pragma unroll
        for (int c = 0; c < 16; ++c) s += part[c][r][k];
        gs[r][k] = relu(dinv[i0 + r] * s);
    }
    __syncthreads();
}

// K2: g1 = relu(dinv*(A@t1)); t2 = dinv*(g1@w2).  256 blocks x 512 thr.
__global__ __launch_bounds__(512) void k_layer1(
        const float* __restrict__ adj, const float* __restrict__ t1,
        const float* __restrict__ dinv, const float* __restrict__ w2,
        float* __restrict__ t2) {
    __shared__ float part[16][3][HD];
    __shared__ float gs[3][HD];
    int tid = threadIdx.x, i0 = blockIdx.x * 3;
    gcn_agg(part, gs, adj, t1, dinv, i0, tid, blockIdx.x);
    if (tid < 3 * HD) {
        int r = tid >> 7, k = tid & 127;
        float acc = 0.f;
        const float* wc = w2 + k;
#pragma unroll
        for (int m4 = 0; m4 < 32; ++m4) {
            float4 gv = *(float4*)&gs[r][m4 * 4];   // LDS broadcast
            acc = fmaf(gv.x, wc[(m4 * 4 + 0) * HD], acc);
            acc = fmaf(gv.y, wc[(m4 * 4 + 1) * HD], acc);
            acc = fmaf(gv.z, wc[(m4 * 4 + 2) * HD], acc);
            acc = fmaf(gv.w, wc[(m4 * 4 + 3) * HD], acc);
        }
        t2[(i0 + r) * HD + k] = dinv[i0 + r] * acc;
    }
}

// K3: g2 = relu(dinv*(A@t2)); p = g2@we1[:H]+cvec, q = g2@we1[H:2H].
__global__ __launch_bounds__(512) void k_layer2(
        const float* __restrict__ adj, const float* __restrict__ t2,
        const float* __restrict__ dinv, const float* __restrict__ we1,
        const float* __restrict__ cvec, float* __restrict__ p, float* __restrict__ q) {
    __shared__ float part[16][3][HD];
    __shared__ float gs[3][HD];
    int tid = threadIdx.x, i0 = blockIdx.x * 3;
    gcn_agg(part, gs, adj, t2, dinv, i0, tid, blockIdx.x);
    if (tid < 3 * HD) {
        int r = tid >> 7, k = tid & 127;
        float ap = 0.f, aq = 0.f;
        const float* wp = we1 + k;
        const float* wq = we1 + HD * HD + k;
#pragma unroll
        for (int m4 = 0; m4 < 32; ++m4) {
            float4 gv = *(float4*)&gs[r][m4 * 4];
            ap = fmaf(gv.x, wp[(m4 * 4 + 0) * HD], ap); aq = fmaf(gv.x, wq[(m4 * 4 + 0) * HD], aq);
            ap = fmaf(gv.y, wp[(m4 * 4 + 1) * HD], ap); aq = fmaf(gv.y, wq[(m4 * 4 + 1) * HD], aq);
            ap = fmaf(gv.z, wp[(m4 * 4 + 2) * HD], ap); aq = fmaf(gv.z, wq[(m4 * 4 + 2) * HD], aq);
            ap = fmaf(gv.w, wp[(m4 * 4 + 3) * HD], ap); aq = fmaf(gv.w, wq[(m4 * 4 + 3) * HD], aq);
        }
        p[(i0 + r) * HD + k] = ap + cvec[k];
        q[(i0 + r) * HD + k] = aq;
    }
}

// K4: 16x16 tile pairs (bi<=bj), 1176 blocks, 256 thr, 1 pair/thread.
__global__ __launch_bounds__(256) void k_pair(
        const float* __restrict__ p, const float* __restrict__ q,
        const float* __restrict__ we2, const float* __restrict__ be2,
        float* __restrict__ out) {
    int t = blockIdx.x;
    int bj = (int)((sqrtf(8.f * t + 1.f) - 1.f) * 0.5f);
    while ((bj + 1) * (bj + 2) / 2 <= t) ++bj;
    while (bj * (bj + 1) / 2 > t) --bj;
    int bi = t - bj * (bj + 1) / 2;
    int i0 = bi * 16, j0 = bj * 16;
    __shared__ float spi[16][132], sqi[16][132], spj[16][132], sqj[16][132];
    __shared__ float w2s[HD];
    __shared__ float vt[16][17];
    int tid = threadIdx.x;
    if (tid < HD) w2s[tid] = we2[tid];
    for (int idx = tid; idx < 512; idx += 256) {
        int r = idx >> 5, c4 = idx & 31;
        *(float4*)&spi[r][c4 * 4] = *(const float4*)&p[(i0 + r) * HD + c4 * 4];
        *(float4*)&sqi[r][c4 * 4] = *(const float4*)&q[(i0 + r) * HD + c4 * 4];
        *(float4*)&spj[r][c4 * 4] = *(const float4*)&p[(j0 + r) * HD + c4 * 4];
        *(float4*)&sqj[r][c4 * 4] = *(const float4*)&q[(j0 + r) * HD + c4 * 4];
    }
    __syncthreads();
    int tx = tid & 15, ty = tid >> 4;
    float aij = 0.f, aji = 0.f;
#pragma unroll 8
    for (int k4 = 0; k4 < 32; ++k4) {
        float4 w  = *(float4*)&w2s[k4 * 4];
        float4 Pi = *(float4*)&spi[ty][k4 * 4];
        float4 Qj = *(float4*)&sqj[tx][k4 * 4];
        float4 Pj = *(float4*)&spj[tx][k4 * 4];
        float4 Qi = *(float4*)&sqi[ty][k4 * 4];
        aij += rdot(Pi, Qj, w);
        aji += rdot(Pj, Qi, w);
    }
    float bias = be2[0];
    float v = 0.5f * (1.f / (1.f + __expf(-(aij + bias)))
                    + 1.f / (1.f + __expf(-(aji + bias))));
    out[(i0 + ty) * NN + (j0 + tx)] = v;
    vt[tx][ty] = v;
    __syncthreads();
    out[(j0 + ty) * NN + (i0 + tx)] = vt[ty][tx];
}

extern "C" void kernel_launch(void* const* d_in, const int* in_sizes, int n_in,
                              void* d_out, int out_size, void* d_ws, size_t ws_size,
                              hipStream_t stream) {
    const float* x    = (const float*)d_in[0];
    const float* adj  = (const float*)d_in[1];
    const float* w1   = (const float*)d_in[2];
    const float* w2   = (const float*)d_in[3];
    const float* temb = (const float*)d_in[4];
    const float* we1  = (const float*)d_in[5];
    const float* be1  = (const float*)d_in[6];
    const float* we2  = (const float*)d_in[7];
    const float* be2  = (const float*)d_in[8];
    const int* tptr   = (const int*)d_in[9];
    float* out        = (float*)d_out;

    float* ws   = (float*)d_ws;
    float* dinv = ws;               // 768
    float* cvec = ws + 768;         // 128
    float* t1   = ws + 1024;        // 768*128
    float* t2   = t1 + NN * HD;
    float* p    = t2 + NN * HD;
    float* q    = p + NN * HD;

    k_prep  <<<257, 768, 0, stream>>>(x, adj, w1, temb, we1, be1, tptr, dinv, cvec, t1);
    k_layer1<<<256, 512, 0, stream>>>(adj, t1, dinv, w2, t2);
    k_layer2<<<256, 512, 0, stream>>>(adj, t2, dinv, we1, cvec, p, q);
    k_pair  <<<1176, 256, 0, stream>>>(p, q, we2, be2, out);
}

// Round 6
// 111.080 us; speedup vs baseline: 1.4706x; 1.0163x over previous
//
#include <hip/hip_runtime.h>

#define NN 768
#define FD 256
#define HD 128

__device__ __forceinline__ float relu(float x) { return x > 0.f ? x : 0.f; }
__device__ __forceinline__ void fma4(float4& a, float s, float4 v) {
    a.x = fmaf(s, v.x, a.x); a.y = fmaf(s, v.y, a.y);
    a.z = fmaf(s, v.z, a.z); a.w = fmaf(s, v.w, a.w);
}
__device__ __forceinline__ float rdot(float4 a, float4 b, float4 w) {
    float s = relu(a.x + b.x) * w.x;
    s = fmaf(relu(a.y + b.y), w.y, s);
    s = fmaf(relu(a.z + b.z), w.z, s);
    s = fmaf(relu(a.w + b.w), w.w, s);
    return s;
}

// K1: blocks 0..255 (768 thr): rows 3b..3b+2 -> dinv[i], t1 = dinv*(x@w1)
//     block 256: cvec[k] = temb[t]@we1[2H:] + be1
// x@w1: 512 threads = 16 m-chunks x 32 k4; float4 w1 loads (4x fewer load insts).
__global__ __launch_bounds__(768) void k_prep(
        const float* __restrict__ x, const float* __restrict__ adj,
        const float* __restrict__ w1, const float* __restrict__ temb,
        const float* __restrict__ we1, const float* __restrict__ be1,
        const int* __restrict__ tptr, float* __restrict__ dinv,
        float* __restrict__ cvec, float* __restrict__ t1D) {
    int b = blockIdx.x, tid = threadIdx.x;
    if (b == 256) {
        __shared__ float ts[HD];
        if (tid < HD) ts[tid] = temb[tptr[0] * HD + tid];
        __syncthreads();
        if (tid < HD) {
            float a0 = be1[tid], a1 = 0.f, a2 = 0.f, a3 = 0.f;
            for (int m = 0; m < HD; m += 4) {
                a0 = fmaf(ts[m + 0], we1[(2 * HD + m + 0) * HD + tid], a0);
                a1 = fmaf(ts[m + 1], we1[(2 * HD + m + 1) * HD + tid], a1);
                a2 = fmaf(ts[m + 2], we1[(2 * HD + m + 2) * HD + tid], a2);
                a3 = fmaf(ts[m + 3], we1[(2 * HD + m + 3) * HD + tid], a3);
            }
            cvec[tid] = (a0 + a1) + (a2 + a3);
        }
        return;
    }
    int i0 = b * 3;
    __shared__ float xs[3][FD];
    __shared__ float partw[16][3][HD];
    __shared__ float red[12];
    __shared__ float sdi[3];
    if (tid < 192) {
        int row = tid >> 6, m4 = tid & 63;
        *(float4*)&xs[row][m4 * 4] = *(const float4*)&x[(i0 + row) * FD + m4 * 4];
    }
    {
        int r2 = tid >> 8, s = tid & 255;
        float sum = 0.f;
        if (s < 192) {
            float4 a = *(const float4*)&adj[(i0 + r2) * NN + s * 4];
            sum = (a.x + a.y) + (a.z + a.w);
        }
#pragma unroll
        for (int off = 32; off > 0; off >>= 1) sum += __shfl_down(sum, off, 64);
        if ((tid & 63) == 0) red[tid >> 6] = sum;
    }
    __syncthreads();
    if (tid < 3) {
        float t = (red[4 * tid] + red[4 * tid + 1]) + (red[4 * tid + 2] + red[4 * tid + 3]);
        float d = rsqrtf(t + 1.f);
        sdi[tid] = d; dinv[i0 + tid] = d;
    }
    if (tid < 512) {
        int k4 = tid & 31, c = tid >> 5;          // m-chunk c*16..c*16+15
        float4 acc0 = {0,0,0,0}, acc1 = {0,0,0,0}, acc2 = {0,0,0,0};
#pragma unroll
        for (int u = 0; u < 16; ++u) {
            int m = c * 16 + u;
            float4 wv = *(const float4*)&w1[m * HD + k4 * 4];
            fma4(acc0, xs[0][m], wv);
            fma4(acc1, xs[1][m], wv);
            fma4(acc2, xs[2][m], wv);
        }
        *(float4*)&partw[c][0][k4 * 4] = acc0;
        *(float4*)&partw[c][1][k4 * 4] = acc1;
        *(float4*)&partw[c][2][k4 * 4] = acc2;
    }
    __syncthreads();
    if (tid < 384) {
        int r = tid >> 7, k = tid & 127;
        float s = 0.f;
#pragma unroll
        for (int c = 0; c < 16; ++c) s += partw[c][r][k];
        t1D[(i0 + r) * HD + k] = sdi[r] * s;
    }
}

// GCN aggregation, 512 thr, 3 rows/block, software-pipelined:
// double-buffered register batches — issue it+1's 14 float4 loads before it's FMAs.
// Block-staggered segment labels (identical arithmetic), adj as uniform float4.
__device__ __forceinline__ void gcn_agg(
        float (*part)[3][HD], float (*gs)[HD],
        const float* __restrict__ adj, const float* __restrict__ tin,
        const float* __restrict__ dinv, int i0, int tid, int b) {
    int k4 = tid & 31, jc = tid >> 5;           // jc 0..15
    int seg = (jc + b) & 15;                    // staggered segment label
    int jbase = seg * 48;
    const float* tb = tin + k4 * 4;
    const float* ar0 = adj + (i0 + 0) * NN;
    const float* ar1 = adj + (i0 + 1) * NN;
    const float* ar2 = adj + (i0 + 2) * NN;
    float4 acc0 = {0,0,0,0}, acc1 = {0,0,0,0}, acc2 = {0,0,0,0};
    float4 A0[2], B0[2], A1[2], B1[2], A2[2], B2[2];
    float4 T0[2], T1[2], T2[2], T3[2], T4[2], T5[2], T6[2], T7[2];
#define LOADB(s, j) do { \
        A0[s] = *(const float4*)&ar0[(j)];     B0[s] = *(const float4*)&ar0[(j) + 4]; \
        A1[s] = *(const float4*)&ar1[(j)];     B1[s] = *(const float4*)&ar1[(j) + 4]; \
        A2[s] = *(const float4*)&ar2[(j)];     B2[s] = *(const float4*)&ar2[(j) + 4]; \
        T0[s] = *(const float4*)&tb[((j)+0)*HD]; T1[s] = *(const float4*)&tb[((j)+1)*HD]; \
        T2[s] = *(const float4*)&tb[((j)+2)*HD]; T3[s] = *(const float4*)&tb[((j)+3)*HD]; \
        T4[s] = *(const float4*)&tb[((j)+4)*HD]; T5[s] = *(const float4*)&tb[((j)+5)*HD]; \
        T6[s] = *(const float4*)&tb[((j)+6)*HD]; T7[s] = *(const float4*)&tb[((j)+7)*HD]; \
    } while (0)
    LOADB(0, jbase);
#pragma unroll
    for (int it = 0; it < 6; ++it) {
        const int cur = it & 1, nxt = cur ^ 1;  // compile-time after full unroll
        if (it < 5) LOADB(nxt, jbase + (it + 1) * 8);
        fma4(acc0, A0[cur].x, T0[cur]); fma4(acc0, A0[cur].y, T1[cur]);
        fma4(acc0, A0[cur].z, T2[cur]); fma4(acc0, A0[cur].w, T3[cur]);
        fma4(acc0, B0[cur].x, T4[cur]); fma4(acc0, B0[cur].y, T5[cur]);
        fma4(acc0, B0[cur].z, T6[cur]); fma4(acc0, B0[cur].w, T7[cur]);
        fma4(acc1, A1[cur].x, T0[cur]); fma4(acc1, A1[cur].y, T1[cur]);
        fma4(acc1, A1[cur].z, T2[cur]); fma4(acc1, A1[cur].w, T3[cur]);
        fma4(acc1, B1[cur].x, T4[cur]); fma4(acc1, B1[cur].y, T5[cur]);
        fma4(acc1, B1[cur].z, T6[cur]); fma4(acc1, B1[cur].w, T7[cur]);
        fma4(acc2, A2[cur].x, T0[cur]); fma4(acc2, A2[cur].y, T1[cur]);
        fma4(acc2, A2[cur].z, T2[cur]); fma4(acc2, A2[cur].w, T3[cur]);
        fma4(acc2, B2[cur].x, T4[cur]); fma4(acc2, B2[cur].y, T5[cur]);
        fma4(acc2, B2[cur].z, T6[cur]); fma4(acc2, B2[cur].w, T7[cur]);
    }
#undef LOADB
    *(float4*)&part[seg][0][k4 * 4] = acc0;
    *(float4*)&part[seg][1][k4 * 4] = acc1;
    *(float4*)&part[seg][2][k4 * 4] = acc2;
    __syncthreads();
    if (tid < 3 * HD) {
        int r = tid >> 7, k = tid & 127;
        float s = tin[(i0 + r) * HD + k];       // self loop (adj + I)
#pragma unroll
        for (int c = 0; c < 16; ++c) s += part[c][r][k];
        gs[r][k] = relu(dinv[i0 + r] * s);
    }
    __syncthreads();
}

// K2: g1 = relu(dinv*(A@t1)); t2 = dinv*(g1@w2).  256 blocks x 512 thr.
__global__ __launch_bounds__(512) void k_layer1(
        const float* __restrict__ adj, const float* __restrict__ t1,
        const float* __restrict__ dinv, const float* __restrict__ w2,
        float* __restrict__ t2) {
    __shared__ float part[16][3][HD];
    __shared__ float gs[3][HD];
    int tid = threadIdx.x, i0 = blockIdx.x * 3;
    gcn_agg(part, gs, adj, t1, dinv, i0, tid, blockIdx.x);
    if (tid < 3 * HD) {
        int r = tid >> 7, k = tid & 127;
        float acc = 0.f;
        const float* wc = w2 + k;
#pragma unroll
        for (int m4 = 0; m4 < 32; ++m4) {
            float4 gv = *(float4*)&gs[r][m4 * 4];   // LDS broadcast
            acc = fmaf(gv.x, wc[(m4 * 4 + 0) * HD], acc);
            acc = fmaf(gv.y, wc[(m4 * 4 + 1) * HD], acc);
            acc = fmaf(gv.z, wc[(m4 * 4 + 2) * HD], acc);
            acc = fmaf(gv.w, wc[(m4 * 4 + 3) * HD], acc);
        }
        t2[(i0 + r) * HD + k] = dinv[i0 + r] * acc;
    }
}

// K3: g2 = relu(dinv*(A@t2)); p = g2@we1[:H]+cvec, q = g2@we1[H:2H].
__global__ __launch_bounds__(512) void k_layer2(
        const float* __restrict__ adj, const float* __restrict__ t2,
        const float* __restrict__ dinv, const float* __restrict__ we1,
        const float* __restrict__ cvec, float* __restrict__ p, float* __restrict__ q) {
    __shared__ float part[16][3][HD];
    __shared__ float gs[3][HD];
    int tid = threadIdx.x, i0 = blockIdx.x * 3;
    gcn_agg(part, gs, adj, t2, dinv, i0, tid, blockIdx.x);
    if (tid < 3 * HD) {
        int r = tid >> 7, k = tid & 127;
        float ap = 0.f, aq = 0.f;
        const float* wp = we1 + k;
        const float* wq = we1 + HD * HD + k;
#pragma unroll
        for (int m4 = 0; m4 < 32; ++m4) {
            float4 gv = *(float4*)&gs[r][m4 * 4];
            ap = fmaf(gv.x, wp[(m4 * 4 + 0) * HD], ap); aq = fmaf(gv.x, wq[(m4 * 4 + 0) * HD], aq);
            ap = fmaf(gv.y, wp[(m4 * 4 + 1) * HD], ap); aq = fmaf(gv.y, wq[(m4 * 4 + 1) * HD], aq);
            ap = fmaf(gv.z, wp[(m4 * 4 + 2) * HD], ap); aq = fmaf(gv.z, wq[(m4 * 4 + 2) * HD], aq);
            ap = fmaf(gv.w, wp[(m4 * 4 + 3) * HD], ap); aq = fmaf(gv.w, wq[(m4 * 4 + 3) * HD], aq);
        }
        p[(i0 + r) * HD + k] = ap + cvec[k];
        q[(i0 + r) * HD + k] = aq;
    }
}

// K4: 16x16 tile pairs (bi<=bj), 1176 blocks, 256 thr, 1 pair/thread.
__global__ __launch_bounds__(256) void k_pair(
        const float* __restrict__ p, const float* __restrict__ q,
        const float* __restrict__ we2, const float* __restrict__ be2,
        float* __restrict__ out) {
    int t = blockIdx.x;
    int bj = (int)((sqrtf(8.f * t + 1.f) - 1.f) * 0.5f);
    while ((bj + 1) * (bj + 2) / 2 <= t) ++bj;
    while (bj * (bj + 1) / 2 > t) --bj;
    int bi = t - bj * (bj + 1) / 2;
    int i0 = bi * 16, j0 = bj * 16;
    __shared__ float spi[16][132], sqi[16][132], spj[16][132], sqj[16][132];
    __shared__ float w2s[HD];
    __shared__ float vt[16][17];
    int tid = threadIdx.x;
    if (tid < HD) w2s[tid] = we2[tid];
    for (int idx = tid; idx < 512; idx += 256) {
        int r = idx >> 5, c4 = idx & 31;
        *(float4*)&spi[r][c4 * 4] = *(const float4*)&p[(i0 + r) * HD + c4 * 4];
        *(float4*)&sqi[r][c4 * 4] = *(const float4*)&q[(i0 + r) * HD + c4 * 4];
        *(float4*)&spj[r][c4 * 4] = *(const float4*)&p[(j0 + r) * HD + c4 * 4];
        *(float4*)&sqj[r][c4 * 4] = *(const float4*)&q[(j0 + r) * HD + c4 * 4];
    }
    __syncthreads();
    int tx = tid & 15, ty = tid >> 4;
    float aij = 0.f, aji = 0.f;
#pragma unroll 8
    for (int k4 = 0; k4 < 32; ++k4) {
        float4 w  = *(float4*)&w2s[k4 * 4];
        float4 Pi = *(float4*)&spi[ty][k4 * 4];
        float4 Qj = *(float4*)&sqj[tx][k4 * 4];
        float4 Pj = *(float4*)&spj[tx][k4 * 4];
        float4 Qi = *(float4*)&sqi[ty][k4 * 4];
        aij += rdot(Pi, Qj, w);
        aji += rdot(Pj, Qi, w);
    }
    float bias = be2[0];
    float v = 0.5f * (1.f / (1.f + __expf(-(aij + bias)))
                    + 1.f / (1.f + __expf(-(aji + bias))));
    out[(i0 + ty) * NN + (j0 + tx)] = v;
    vt[tx][ty] = v;
    __syncthreads();
    out[(j0 + ty) * NN + (i0 + tx)] = vt[ty][tx];
}

extern "C" void kernel_launch(void* const* d_in, const int* in_sizes, int n_in,
                              void* d_out, int out_size, void* d_ws, size_t ws_size,
                              hipStream_t stream) {
    const float* x    = (const float*)d_in[0];
    const float* adj  = (const float*)d_in[1];
    const float* w1   = (const float*)d_in[2];
    const float* w2   = (const float*)d_in[3];
    const float* temb = (const float*)d_in[4];
    const float* we1  = (const float*)d_in[5];
    const float* be1  = (const float*)d_in[6];
    const float* we2  = (const float*)d_in[7];
    const float* be2  = (const float*)d_in[8];
    const int* tptr   = (const int*)d_in[9];
    float* out        = (float*)d_out;

    float* ws   = (float*)d_ws;
    float* dinv = ws;               // 768
    float* cvec = ws + 768;         // 128
    float* t1   = ws + 1024;        // 768*128
    float* t2   = t1 + NN * HD;
    float* p    = t2 + NN * HD;
    float* q    = p + NN * HD;

    k_prep  <<<257, 768, 0, stream>>>(x, adj, w1, temb, we1, be1, tptr, dinv, cvec, t1);
    k_layer1<<<256, 512, 0, stream>>>(adj, t1, dinv, w2, t2);
    k_layer2<<<256, 512, 0, stream>>>(adj, t2, dinv, we1, cvec, p, q);
    k_pair  <<<1176, 256, 0, stream>>>(p, q, we2, be2, out);
}